// Round 6
// baseline (413.365 us; speedup 1.0000x reference)
//
#include <hip/hip_runtime.h>
#include <hip/hip_bf16.h>

typedef __attribute__((ext_vector_type(8))) short short8;
typedef __attribute__((ext_vector_type(4))) float f32x4;
typedef unsigned short ushort;

#define BB 128
#define HHH 16
#define WWW 48
#define DD 512
#define UU 512
#define ROWS_PER_B (HHH * WWW)      /* 768 */
#define MTOT (BB * ROWS_PER_B)      /* 98304 */
#define BM 64
#define BN 256
#define BK 64

__device__ __forceinline__ ushort f2bf(float f) {      // round-half-up
    return (ushort)((__float_as_uint(f) + 0x8000u) >> 16);
}
__device__ __forceinline__ float bf2f(ushort u) {
    return __uint_as_float(((unsigned)u) << 16);
}
__device__ __forceinline__ void gload_lds16(const ushort* g, ushort* l) {
    __builtin_amdgcn_global_load_lds(
        (const __attribute__((address_space(1))) unsigned int*)(const void*)g,
        (__attribute__((address_space(3))) unsigned int*)(void*)l,
        16, 0, 0);
}

// ============================ NEW PATH =====================================
// prep2: grid 1664 blocks x 256 thr.
//  blocks 0..63    : dproj split-K partials (atomicAdd into zeroed dproj)
//  blocks 64..127  : pack W1 (D,U) fp32 -> w1p[kc][u][s^(u&7)] bf16
//  blocks 128..1663: enc fp32 -> encp packed swizzled bf16 (64-row tiles)
__global__ __launch_bounds__(256) void prep2_kernel(
        const float* __restrict__ enc, const float* __restrict__ w1,
        const float* __restrict__ dec, const float* __restrict__ w2,
        ushort* __restrict__ encp, ushort* __restrict__ w1p,
        float* __restrict__ dproj) {
    __shared__ __align__(16) char smem[32768];
    const int t = threadIdx.x;
    const int bid = blockIdx.x;

    if (bid < 64) {
        // ---- dproj partial: uq = bid&7 (64 u), kp = bid>>3 (64 d) ----
        const int u0 = (bid & 7) * 64;
        const int d0 = (bid >> 3) * 64;
        const int u  = t & 63;
        const int bq = t >> 6;               // 0..3 -> 32 b each
        float w2r[64];
#pragma unroll
        for (int dd = 0; dd < 64; ++dd)
            w2r[dd] = w2[(size_t)(d0 + dd) * UU + u0 + u];
        float* decs = (float*)smem;          // [128][64]
        for (int i = t; i < 8192; i += 256)
            decs[i] = dec[(size_t)(i >> 6) * DD + d0 + (i & 63)];
        __syncthreads();
        for (int j = 0; j < 32; ++j) {
            const float* dr = &decs[(bq * 32 + j) * 64];
            float s = 0.f;
#pragma unroll
            for (int dd = 0; dd < 64; ++dd) s = fmaf(dr[dd], w2r[dd], s);
            atomicAdd(&dproj[(size_t)(bq * 32 + j) * UU + u0 + u], s);
        }
    } else if (bid < 128) {
        // ---- pack W1 ----
        const int pb = bid - 64;
        ushort* tile = (ushort*)smem;        // [64][72]
        const int u0 = (pb & 7) * 64;
        const int kc = pb >> 3;
        const int ul = t & 63;
        const int db = t >> 6;
#pragma unroll
        for (int i = 0; i < 16; ++i) {
            const int d = db + i * 4;
            tile[ul * 72 + d] = f2bf(w1[(size_t)(kc * 64 + d) * UU + u0 + ul]);
        }
        __syncthreads();
        const int u = t >> 2;
        const int s = (t & 3) * 2;
        const int x = u & 7;
        short8 v0 = *(const short8*)&tile[u * 72 + s * 8];
        short8 v1 = *(const short8*)&tile[u * 72 + s * 8 + 8];
        *(short8*)&w1p[(size_t)kc * 32768 + (u0 + u) * 64 + (( s      ^ x)) * 8] = v0;
        *(short8*)&w1p[(size_t)kc * 32768 + (u0 + u) * 64 + (((s + 1) ^ x)) * 8] = v1;
    } else {
        // ---- enc -> encp (64-row tile, swizzled bf16) ----
        const int mt  = bid - 128;           // 0..1535
        const int row = t >> 2;
        const int cb  = (t & 3) * 2;         // chunk base 0,2,4,6
        const float* src = enc + ((size_t)mt * 64 + row) * DD + cb * 8;
        ushort* dst = encp + (size_t)mt * 32768 + row * 64;
        const int s0 = ( cb      ^ (row & 7)) * 8;
        const int s1 = ((cb + 1) ^ (row & 7)) * 8;
#pragma unroll
        for (int kc = 0; kc < 8; ++kc) {
            const float* s4 = src + kc * 64;
            float4 a0 = ((const float4*)s4)[0];
            float4 a1 = ((const float4*)s4)[1];
            float4 a2 = ((const float4*)s4)[2];
            float4 a3 = ((const float4*)s4)[3];
            short8 w0, w1v;
            ushort* p0 = (ushort*)&w0; ushort* p1 = (ushort*)&w1v;
            p0[0]=f2bf(a0.x); p0[1]=f2bf(a0.y); p0[2]=f2bf(a0.z); p0[3]=f2bf(a0.w);
            p0[4]=f2bf(a1.x); p0[5]=f2bf(a1.y); p0[6]=f2bf(a1.z); p0[7]=f2bf(a1.w);
            p1[0]=f2bf(a2.x); p1[1]=f2bf(a2.y); p1[2]=f2bf(a2.z); p1[3]=f2bf(a2.w);
            p1[4]=f2bf(a3.x); p1[5]=f2bf(a3.y); p1[6]=f2bf(a3.z); p1[7]=f2bf(a3.w);
            *(short8*)&dst[kc * 4096 + s0] = w0;
            *(short8*)&dst[kc * 4096 + s1] = w1v;
        }
    }
}

// score2: pure-DMA staged GEMM. Block: 64 m x 256 u (half), BK=64, 4 waves,
// A+B double-buffered (80 KB -> 2 blocks/CU), one barrier per K-step.
__global__ __launch_bounds__(256, 2) void score2_kernel(
        const ushort* __restrict__ encp, const ushort* __restrict__ w1p,
        const float* __restrict__ dproj, const float* __restrict__ w1b,
        const float* __restrict__ w2b, const float* __restrict__ vw,
        float* __restrict__ scorep) {
    __shared__ __align__(16) ushort Bb[2][BN * BK];    // 2 x 32 KB
    __shared__ __align__(16) ushort Ab[2][BM * BK];    // 2 x 8 KB

    const int tid  = threadIdx.x;
    const int lane = tid & 63;
    const int wave = tid >> 6;               // u-chunk 0..3
    const int wg   = blockIdx.x;
    const int mt   = (wg & 7) * 192 + ((wg >> 3) >> 1);   // XCD-chunked
    const int half = (wg >> 3) & 1;
    const int mbase = mt * 64;
    const int b = mt / 12;
    const int lrow = lane & 15;
    const int kgrp = lane >> 4;

    const ushort* asrc0 = encp + (size_t)mt * 32768 + tid * 8;
    const ushort* bsrc0 = w1p + half * 16384 + tid * 8;

    f32x4 acc[4][4] = {};

    // prologue: stage kc=0 into buf 0
    gload_lds16(asrc0,        &Ab[0][tid * 8]);
    gload_lds16(asrc0 + 2048, &Ab[0][tid * 8 + 2048]);
#pragma unroll
    for (int i = 0; i < 8; ++i)
        gload_lds16(bsrc0 + i * 2048, &Bb[0][tid * 8 + i * 2048]);
    asm volatile("s_waitcnt vmcnt(0)" ::: "memory");
    __syncthreads();

    for (int kc = 0; kc < 8; ++kc) {
        const int cur = kc & 1;
        if (kc < 7) {                        // issue next-tile DMA early
            const ushort* an = asrc0 + (kc + 1) * 4096;
            const ushort* bn = bsrc0 + (size_t)(kc + 1) * 32768;
            gload_lds16(an,        &Ab[cur ^ 1][tid * 8]);
            gload_lds16(an + 2048, &Ab[cur ^ 1][tid * 8 + 2048]);
#pragma unroll
            for (int i = 0; i < 8; ++i)
                gload_lds16(bn + i * 2048, &Bb[cur ^ 1][tid * 8 + i * 2048]);
        }
        const ushort* Bc = &Bb[cur][0];
        const ushort* Ac = &Ab[cur][0];
#pragma unroll
        for (int kk = 0; kk < 2; ++kk) {
            const int sub = kk * 4 + kgrp;
            short8 afr[4], bfr[4];
#pragma unroll
            for (int ms = 0; ms < 4; ++ms) {
                const int r = ms * 16 + lrow;
                afr[ms] = *(const short8*)&Ac[r * 64 + (sub ^ (r & 7)) * 8];
            }
#pragma unroll
            for (int uf = 0; uf < 4; ++uf) {
                const int u = wave * 64 + uf * 16 + lrow;
                bfr[uf] = *(const short8*)&Bc[u * 64 + (sub ^ (u & 7)) * 8];
            }
#pragma unroll
            for (int ms = 0; ms < 4; ++ms)
#pragma unroll
                for (int uf = 0; uf < 4; ++uf)
                    acc[ms][uf] = __builtin_amdgcn_mfma_f32_16x16x32_bf16(
                        afr[ms], bfr[uf], acc[ms][uf], 0, 0, 0);
        }
        asm volatile("s_waitcnt vmcnt(0)" ::: "memory");
        __syncthreads();
    }

    // epilogue: + dproj+biases, fast tanh, dot V_w, reduce over u
    const float C2 = 2.8853900817779268f;    // 2*log2(e)
    float part[4][4] = {};
#pragma unroll
    for (int uf = 0; uf < 4; ++uf) {
        const int u = half * 256 + wave * 64 + uf * 16 + lrow;
        const float cadd = dproj[b * UU + u] + w1b[u] + w2b[u];
        const float vwe  = vw[u];
#pragma unroll
        for (int ms = 0; ms < 4; ++ms)
#pragma unroll
            for (int j = 0; j < 4; ++j) {
                float x = acc[ms][uf][j] + cadd;
                float e = __builtin_amdgcn_exp2f(x * C2);
                float r = __builtin_amdgcn_rcpf(1.f + e);
                float h = fmaf(-2.f, r, 1.f);            // tanh(x)
                part[ms][j] = fmaf(vwe, h, part[ms][j]);
            }
    }
#pragma unroll
    for (int off = 1; off < 16; off <<= 1)
#pragma unroll
        for (int ms = 0; ms < 4; ++ms)
#pragma unroll
            for (int j = 0; j < 4; ++j)
                part[ms][j] += __shfl_xor(part[ms][j], off, 64);

    float* scr = (float*)&Ab[0][0];
    if (lrow == 0) {
#pragma unroll
        for (int ms = 0; ms < 4; ++ms)
#pragma unroll
            for (int j = 0; j < 4; ++j)
                scr[wave * 64 + ms * 16 + kgrp * 4 + j] = part[ms][j];
    }
    __syncthreads();
    if (tid < 64)
        scorep[(size_t)half * MTOT + mbase + tid] =
            scr[tid] + scr[64 + tid] + scr[128 + tid] + scr[192 + tid];
}

// ctx2: grid (8, B) x 256. Softmax per b in LDS; write 96 attn rows; 96-row
// bf16 context partial per row-phase (32 slices / b).
__global__ __launch_bounds__(256) void ctx2_kernel(
        const float* __restrict__ scorep, const ushort* __restrict__ encp,
        const float* __restrict__ vb, float* __restrict__ attn,
        float* __restrict__ partial) {
    __shared__ float sl[ROWS_PER_B];
    __shared__ float al[ROWS_PER_B];
    const int q = blockIdx.x;
    const int b = blockIdx.y;
    const int t = threadIdx.x;
    const float vbv = vb[0];
    for (int i = t; i < ROWS_PER_B; i += 256)
        sl[i] = scorep[b * ROWS_PER_B + i] + scorep[MTOT + b * ROWS_PER_B + i] + vbv;
    __syncthreads();
    if (t < WWW) {
        float v[HHH];
        float m = -1e30f;
#pragma unroll
        for (int h = 0; h < HHH; ++h) { v[h] = sl[h * WWW + t]; m = fmaxf(m, v[h]); }
        float sum = 0.f;
#pragma unroll
        for (int h = 0; h < HHH; ++h) { v[h] = __expf(v[h] - m); sum += v[h]; }
        const float inv = 1.f / sum;
#pragma unroll
        for (int h = 0; h < HHH; ++h) al[h * WWW + t] = v[h] * inv;
    }
    __syncthreads();
    if (t < 96) attn[b * ROWS_PER_B + q * 96 + t] = al[q * 96 + t];

    const int rp = t >> 6;                   // 0..3
    const int g8 = t & 63;                   // 8-elem chunk 0..63
    const int kc = g8 >> 3;
    float fa[8] = {};
#pragma unroll 4
    for (int i = 0; i < 24; ++i) {
        const int r = q * 96 + rp + i * 4;
        const float a = al[r];
        const size_t gr = (size_t)b * ROWS_PER_B + r;
        const ushort* p = encp + (gr >> 6) * 32768 + kc * 4096 + (gr & 63) * 64
                        + (((g8 & 7) ^ (r & 7)) * 8);
        short8 v = *(const short8*)p;
#pragma unroll
        for (int j = 0; j < 8; ++j)
            fa[j] = fmaf(a, bf2f((ushort)v[j]), fa[j]);
    }
    float* dst = partial + ((size_t)((b * 8 + q) * 4 + rp)) * DD + g8 * 8;
    float4 o0 = {fa[0], fa[1], fa[2], fa[3]};
    float4 o1 = {fa[4], fa[5], fa[6], fa[7]};
    ((float4*)dst)[0] = o0;
    ((float4*)dst)[1] = o1;
}

__global__ void reduce2_kernel(const float* __restrict__ partial,
                               float* __restrict__ out) {
    const int qd = blockIdx.x * 256 + threadIdx.x;   // 16384 quads
    const int b = qd >> 7;
    const int d4 = (qd & 127) * 4;
    float4 s = {0.f, 0.f, 0.f, 0.f};
#pragma unroll
    for (int j = 0; j < 32; ++j) {
        const float4 p = *(const float4*)(partial + ((size_t)(b * 32 + j)) * DD + d4);
        s.x += p.x; s.y += p.y; s.z += p.z; s.w += p.w;
    }
    *(float4*)(out + (size_t)b * DD + d4) = s;
}

// ============================ FALLBACK (round-5) ===========================
__global__ __launch_bounds__(256) void prep_fb(
        const float* __restrict__ w1, const float* __restrict__ dec,
        const float* __restrict__ w2, const float* __restrict__ w1b,
        const float* __restrict__ w2b,
        ushort* __restrict__ w1p, float* __restrict__ dproj) {
    const int t = threadIdx.x;
    if (blockIdx.x < 64) {
        __shared__ __align__(16) ushort tile[64 * 72];
        const int u0 = (blockIdx.x & 7) * 64;
        const int kc = blockIdx.x >> 3;
        const int ul = t & 63;
        const int db = t >> 6;
#pragma unroll
        for (int i = 0; i < 16; ++i) {
            const int d = db + i * 4;
            tile[ul * 72 + d] = f2bf(w1[(size_t)(kc * 64 + d) * UU + u0 + ul]);
        }
        __syncthreads();
        const int u = t >> 2;
        const int s = (t & 3) * 2;
        const int x = u & 7;
        short8 v0 = *(const short8*)&tile[u * 72 + s * 8];
        short8 v1 = *(const short8*)&tile[u * 72 + s * 8 + 8];
        *(short8*)&w1p[(size_t)kc * 32768 + (u0 + u) * 64 + (( s      ^ x)) * 8] = v0;
        *(short8*)&w1p[(size_t)kc * 32768 + (u0 + u) * 64 + (((s + 1) ^ x)) * 8] = v1;
    } else {
        const int g = blockIdx.x - 64;
        const int b = g >> 1;
        const int u = (g & 1) * 256 + t;
        float acc = 0.f;
#pragma unroll 8
        for (int d = 0; d < DD; ++d)
            acc += dec[b * DD + d] * w2[(size_t)d * UU + u];
        dproj[b * UU + u] = acc + w1b[u] + w2b[u];
    }
}

__global__ __launch_bounds__(256, 4) void score_fb(
        const float* __restrict__ enc, const ushort* __restrict__ w1p,
        const float* __restrict__ dproj, const float* __restrict__ vw,
        float* __restrict__ scorep) {
    __shared__ __align__(16) ushort Bb[BN * BK];
    __shared__ __align__(16) ushort Ab[BM * BK];
    const int tid  = threadIdx.x;
    const int lane = tid & 63;
    const int wave = tid >> 6;
    const int mbase = blockIdx.x * BM;
    const int half  = blockIdx.y;
    const int b = mbase / ROWS_PER_B;
    const int lrow = lane & 15;
    const int kgrp = lane >> 4;
    const int ar  = tid >> 2;
    const int ac  = (tid & 3) * 2;
    const float* abase = enc + (size_t)(mbase + ar) * DD + ac * 8;
    const int s0p = ( ac      ^ (ar & 7)) * 8;
    const int s1p = ((ac + 1) ^ (ar & 7)) * 8;
    const ushort* bsrc0 = w1p + half * 16384 + tid * 8;
    f32x4 acc[4][4] = {};
    for (int kc = 0; kc < 8; ++kc) {
        const ushort* bsrc = bsrc0 + (size_t)kc * 32768;
#pragma unroll
        for (int i = 0; i < 8; ++i)
            gload_lds16(bsrc + i * 2048, &Bb[tid * 8 + i * 2048]);
        {
            const float* asrc = abase + kc * 64;
            float4 a0 = ((const float4*)asrc)[0];
            float4 a1 = ((const float4*)asrc)[1];
            float4 a2 = ((const float4*)asrc)[2];
            float4 a3 = ((const float4*)asrc)[3];
            short8 w0, w1v;
            ushort* p0 = (ushort*)&w0; ushort* p1 = (ushort*)&w1v;
            p0[0]=f2bf(a0.x); p0[1]=f2bf(a0.y); p0[2]=f2bf(a0.z); p0[3]=f2bf(a0.w);
            p0[4]=f2bf(a1.x); p0[5]=f2bf(a1.y); p0[6]=f2bf(a1.z); p0[7]=f2bf(a1.w);
            p1[0]=f2bf(a2.x); p1[1]=f2bf(a2.y); p1[2]=f2bf(a2.z); p1[3]=f2bf(a2.w);
            p1[4]=f2bf(a3.x); p1[5]=f2bf(a3.y); p1[6]=f2bf(a3.z); p1[7]=f2bf(a3.w);
            *(short8*)&Ab[ar * 64 + s0p] = w0;
            *(short8*)&Ab[ar * 64 + s1p] = w1v;
        }
        __syncthreads();
#pragma unroll
        for (int kk = 0; kk < 2; ++kk) {
            const int sub = kk * 4 + kgrp;
            short8 afr[4], bfr[4];
#pragma unroll
            for (int ms = 0; ms < 4; ++ms) {
                const int r = ms * 16 + lrow;
                afr[ms] = *(const short8*)&Ab[r * 64 + (sub ^ (r & 7)) * 8];
            }
#pragma unroll
            for (int uf = 0; uf < 4; ++uf) {
                const int u = wave * 64 + uf * 16 + lrow;
                bfr[uf] = *(const short8*)&Bb[u * 64 + (sub ^ (u & 7)) * 8];
            }
#pragma unroll
            for (int ms = 0; ms < 4; ++ms)
#pragma unroll
                for (int uf = 0; uf < 4; ++uf)
                    acc[ms][uf] = __builtin_amdgcn_mfma_f32_16x16x32_bf16(
                        afr[ms], bfr[uf], acc[ms][uf], 0, 0, 0);
        }
        __syncthreads();
    }
    float part[4][4] = {};
#pragma unroll
    for (int uf = 0; uf < 4; ++uf) {
        const int u = half * 256 + wave * 64 + uf * 16 + lrow;
        const float cadd = dproj[b * UU + u];
        const float vwe  = vw[u];
#pragma unroll
        for (int ms = 0; ms < 4; ++ms)
#pragma unroll
            for (int j = 0; j < 4; ++j) {
                float x = acc[ms][uf][j] + cadd;
                x = fminf(fmaxf(x, -15.f), 15.f);
                float e = __expf(2.f * x);
                part[ms][j] += vwe * ((e - 1.f) / (e + 1.f));
            }
    }
#pragma unroll
    for (int off = 1; off < 16; off <<= 1)
#pragma unroll
        for (int ms = 0; ms < 4; ++ms)
#pragma unroll
            for (int j = 0; j < 4; ++j)
                part[ms][j] += __shfl_xor(part[ms][j], off, 64);
    float* scr = (float*)&Ab[0];
    if (lrow == 0) {
#pragma unroll
        for (int ms = 0; ms < 4; ++ms)
#pragma unroll
            for (int j = 0; j < 4; ++j)
                scr[wave * 64 + ms * 16 + kgrp * 4 + j] = part[ms][j];
    }
    __syncthreads();
    if (tid < 64)
        scorep[(size_t)half * MTOT + mbase + tid] =
            scr[tid] + scr[64 + tid] + scr[128 + tid] + scr[192 + tid];
}

__global__ __launch_bounds__(512) void ctx_fb(
        const float* __restrict__ scorep, const float* __restrict__ enc,
        const float* __restrict__ vb,
        float* __restrict__ attn, float* __restrict__ partial) {
    __shared__ float sl[ROWS_PER_B];
    __shared__ float al[ROWS_PER_B];
    const int q = blockIdx.x;
    const int b = blockIdx.y;
    const int t = threadIdx.x;
    const float vbv = vb[0];
    for (int i = t; i < ROWS_PER_B; i += 512)
        sl[i] = scorep[b * ROWS_PER_B + i] + scorep[MTOT + b * ROWS_PER_B + i] + vbv;
    __syncthreads();
    if (t < WWW) {
        float v[HHH];
        float m = -1e30f;
#pragma unroll
        for (int h = 0; h < HHH; ++h) { v[h] = sl[h * WWW + t]; m = fmaxf(m, v[h]); }
        float sum = 0.f;
#pragma unroll
        for (int h = 0; h < HHH; ++h) { v[h] = __expf(v[h] - m); sum += v[h]; }
        const float inv = 1.f / sum;
#pragma unroll
        for (int h = 0; h < HHH; ++h) al[h * WWW + t] = v[h] * inv;
    }
    __syncthreads();
    const int rb = q * 192;
    for (int i = t; i < 192; i += 512)
        attn[b * ROWS_PER_B + rb + i] = al[rb + i];
    const int r0 = t >> 7;
    const int d4 = (t & 127) * 4;
    float4 acc = {0.f, 0.f, 0.f, 0.f};
    const float* ebase = enc + ((size_t)b * ROWS_PER_B + rb) * DD + d4;
#pragma unroll 8
    for (int i = 0; i < 48; ++i) {
        const int r = r0 + i * 4;
        const float a = al[rb + r];
        const float4 e = *(const float4*)(ebase + (size_t)r * DD);
        acc.x += a * e.x; acc.y += a * e.y; acc.z += a * e.z; acc.w += a * e.w;
    }
    *(float4*)(partial + ((size_t)((b * 4 + q) * 4 + r0)) * DD + d4) = acc;
}

__global__ void reduce_fb(const float* __restrict__ partial,
                          float* __restrict__ out) {
    const int qd = blockIdx.x * 256 + threadIdx.x;
    const int b = qd >> 7;
    const int d4 = (qd & 127) * 4;
    float4 s = {0.f, 0.f, 0.f, 0.f};
#pragma unroll
    for (int j = 0; j < 16; ++j) {
        const float4 p = *(const float4*)(partial + ((size_t)(b * 16 + j)) * DD + d4);
        s.x += p.x; s.y += p.y; s.z += p.z; s.w += p.w;
    }
    *(float4*)(out + (size_t)b * DD + d4) = s;
}

// ===========================================================================
extern "C" void kernel_launch(void* const* d_in, const int* in_sizes, int n_in,
                              void* d_out, int out_size, void* d_ws, size_t ws_size,
                              hipStream_t stream) {
    const float* dec = (const float*)d_in[0];
    const float* enc = (const float*)d_in[1];
    const float* w1w = (const float*)d_in[2];
    const float* w1b = (const float*)d_in[3];
    const float* w2w = (const float*)d_in[4];
    const float* w2b = (const float*)d_in[5];
    const float* vw  = (const float*)d_in[6];
    const float* vb  = (const float*)d_in[7];

    float* out = (float*)d_out;
    float* ctx  = out;                 // (B, D)
    float* attn = out + BB * DD;       // (B,H,W,1)
    char* ws = (char*)d_ws;

    const size_t ENCP_B   = (size_t)MTOT * DD * 2;           // 100,663,296
    const size_t W1P_B    = (size_t)UU * DD * 2;             // 524,288
    const size_t DPROJ_B  = (size_t)BB * UU * 4;             // 262,144
    const size_t SCOREP_B = (size_t)2 * MTOT * 4;            // 786,432
    const size_t PART_B   = (size_t)BB * 32 * DD * 4;        // 8,388,608
    const size_t NEED = ENCP_B + W1P_B + DPROJ_B + SCOREP_B + PART_B;

    if (ws_size >= NEED) {
        ushort* encp   = (ushort*)(ws);
        ushort* w1p    = (ushort*)(ws + ENCP_B);
        float*  dproj  = (float*)(ws + ENCP_B + W1P_B);
        float*  scorep = (float*)(ws + ENCP_B + W1P_B + DPROJ_B);
        float*  partial= (float*)(ws + ENCP_B + W1P_B + DPROJ_B + SCOREP_B);

        hipMemsetAsync(dproj, 0, DPROJ_B, stream);
        prep2_kernel<<<1664, 256, 0, stream>>>(enc, w1w, dec, w2w, encp, w1p, dproj);
        score2_kernel<<<3072, 256, 0, stream>>>(encp, w1p, dproj, w1b, w2b, vw, scorep);
        ctx2_kernel<<<dim3(8, BB), 256, 0, stream>>>(scorep, encp, vb, attn, partial);
        reduce2_kernel<<<64, 256, 0, stream>>>(partial, ctx);
    } else {
        ushort* w1p    = (ushort*)(ws);
        float*  dproj  = (float*)(ws + (512 << 10));
        float*  scorep = (float*)(ws + (768 << 10));
        float*  partial= (float*)(ws + (1536 << 10));
        prep_fb<<<320, 256, 0, stream>>>(w1w, dec, w2w, w1b, w2b, w1p, dproj);
        score_fb<<<dim3(MTOT / BM, 2), 256, 0, stream>>>(enc, w1p, dproj, vw, scorep);
        ctx_fb<<<dim3(4, BB), 512, 0, stream>>>(scorep, enc, vb, attn, partial);
        reduce_fb<<<64, 256, 0, stream>>>(partial, ctx);
    }
}